// Round 5
// baseline (763.424 us; speedup 1.0000x reference)
//
#include <hip/hip_runtime.h>

#define NEXP 8
#define E_TOT 100000
#define NTILE 391  // ceil(E/256)

typedef __bf16 bf16x8 __attribute__((ext_vector_type(8)));
typedef float f32x4 __attribute__((ext_vector_type(4)));
typedef unsigned short u16x8 __attribute__((ext_vector_type(8)));

union BF8 { u16x8 u; bf16x8 b; };

__device__ __forceinline__ unsigned short f2bf(float f) {
  unsigned int u = __float_as_uint(f);
  u += 0x7fffu + ((u >> 16) & 1u);           // RNE
  return (unsigned short)(u >> 16);
}

// RNE pack of two floats into one u32 of 2xbf16 (lo in [15:0], hi in [31:16]).
__device__ __forceinline__ unsigned pack2(float lo, float hi) {
  return (unsigned)f2bf(lo) | ((unsigned)f2bf(hi) << 16);
}

// XOR-swizzled element index: row r, col c, row stride (elems).
__device__ __forceinline__ int sidx(int r, int c, int stride) {
  return r * stride + (c ^ ((r & 7) << 3));
}

__device__ __forceinline__ bf16x8 fragld(const unsigned short* a, int off) {
  BF8 t;
  t.u = *(const u16x8*)(a + off);
  return t.b;
}

__device__ __forceinline__ void stage8(unsigned short* dst, const float* src) {
  float4 a = *(const float4*)(src);
  float4 b = *(const float4*)(src + 4);
  BF8 t;
  t.u[0]=f2bf(a.x); t.u[1]=f2bf(a.y); t.u[2]=f2bf(a.z); t.u[3]=f2bf(a.w);
  t.u[4]=f2bf(b.x); t.u[5]=f2bf(b.y); t.u[6]=f2bf(b.z); t.u[7]=f2bf(b.w);
  *(u16x8*)dst = t.u;
}

// ---- pre-kernel: weights fp32 -> bf16, PRE-SWIZZLED to LDS-linear order ----
__global__ void k_conv_w(const float* __restrict__ W1c, const float* __restrict__ W2p,
                         const float* __restrict__ W3p, unsigned short* __restrict__ wsW) {
  int gid = blockIdx.x * 256 + threadIdx.x;     // [0, 262144)
  int n = gid >> 15, p = gid & 32767;
  float v;
  if (p < 8192) {
    int r = p >> 6, cs = p & 63;
    v = W1c[(size_t)n * 8192 + r * 64 + (cs ^ ((r & 7) << 3))];
  } else if (p < 24576) {
    int q = p - 8192; int r = q >> 7, cs = q & 127;
    v = W2p[(size_t)n * 16384 + r * 128 + (cs ^ ((r & 7) << 3))];
  } else {
    int q = p - 24576; int r = q >> 7, cs = q & 127;
    v = W3p[(size_t)n * 8192 + r * 128 + (cs ^ ((r & 7) << 3))];
  }
  wsW[gid] = f2bf(v);
}

// ---- pre-kernel: x fp32 -> bf16 ----
__global__ void k_conv_x(const float* __restrict__ xg, unsigned short* __restrict__ xb) {
  int gid = blockIdx.x * 256 + threadIdx.x;     // 800000 threads, 8 elems each
  const float* s = xg + (size_t)gid * 8;
  stage8(xb + (size_t)gid * 8, s);
}

// ---- main kernel: swapped-operand (D = W . x^T), activations in registers,
//      D->B relayout via small per-wave LDS roundtrip (R1-validated path) ----
template <bool USEWS>
__global__ __launch_bounds__(512, 4) void k_main(
    const unsigned short* __restrict__ wsW, const unsigned short* __restrict__ xb,
    const float* __restrict__ xg,
    const float* __restrict__ W1c, const float* __restrict__ b1c,
    const float* __restrict__ g1p, const float* __restrict__ bt1p,
    const float* __restrict__ W2p, const float* __restrict__ b2p,
    const float* __restrict__ g2p, const float* __restrict__ bt2p,
    const float* __restrict__ W3p, const float* __restrict__ b3p,
    float* __restrict__ outp)
{
  __shared__ __attribute__((aligned(16))) unsigned short wsm[32768];  // 64 KB weights (swizzled)
  __shared__ __attribute__((aligned(16))) unsigned short act[128*40]; // 10 KB relayout scratch
  __shared__ __attribute__((aligned(16))) float prm[832];             // LN params + b3

  // bijective remap: flat bid -> (tile, expert); each XCD (bid%8) owns a
  // contiguous tile range with all 8 experts -> x slab fetched once/XCD
  const int bid = blockIdx.x;
  const int g_  = (bid & 7) * NTILE + (bid >> 3);
  const int tile = g_ >> 3;
  const int n    = g_ & 7;
  const int e0   = tile * 256;

  const int tid  = threadIdx.x;
  const int lane = tid & 63;
  const int wv   = tid >> 6;
  const int l15  = lane & 15;
  const int gq   = lane >> 4;          // 0..3
  const int wrow = wv * 32;            // wave's 32 edges within tile

  // ---- stage weights into LDS ----
  if (USEWS) {
    const unsigned short* src = wsW + (size_t)n * 32768;
#pragma unroll
    for (int i = 0; i < 8; ++i) {
      int c8 = tid + i * 512;          // u16x8 chunk id, 4096 total
      *(u16x8*)&wsm[c8 * 8] = *(const u16x8*)&src[c8 * 8];
    }
  } else {
    const float* s1 = W1c + (size_t)n * 8192;
#pragma unroll
    for (int i = 0; i < 2; ++i) {
      int c = tid + i * 512; int r = c >> 3, co = (c & 7) << 3;
      stage8(&wsm[sidx(r, co, 64)], s1 + r * 64 + co);
    }
    const float* s2 = W2p + (size_t)n * 16384;
#pragma unroll
    for (int i = 0; i < 4; ++i) {
      int c = tid + i * 512; int r = c >> 4, co = (c & 15) << 3;
      stage8(&wsm[8192 + sidx(r, co, 128)], s2 + r * 128 + co);
    }
    const float* s3 = W3p + (size_t)n * 8192;
#pragma unroll
    for (int i = 0; i < 2; ++i) {
      int c = tid + i * 512; int r = c >> 4, co = (c & 15) << 3;
      stage8(&wsm[24576 + sidx(r, co, 128)], s3 + r * 128 + co);
    }
  }
  // ---- stage LN params (832 slots, 512 threads -> strided loop) ----
  for (int i = tid; i < 832; i += 512) {
    int grp = i >> 7, f = i & 127;
    float v;
    switch (grp) {
      case 0: v = b1c [n * 128 + f]; break;
      case 1: v = g1p [n * 128 + f]; break;
      case 2: v = bt1p[n * 128 + f]; break;
      case 3: v = b2p [n * 128 + f]; break;
      case 4: v = g2p [n * 128 + f]; break;
      case 5: v = bt2p[n * 128 + f]; break;
      default: v = b3p[n * 64 + f]; break;   // i in 768..831, f = i-768
    }
    prm[i] = v;
  }

  // ---- x B-fragments: lane holds x[edge = l15+16et][d = 8gq+j+32s] ----
  bf16x8 bx[2][2];
#pragma unroll
  for (int et = 0; et < 2; ++et) {
    int e = e0 + wrow + 16 * et + l15;
    if (e >= E_TOT) e = E_TOT - 1;
    if (USEWS) {
#pragma unroll
      for (int s = 0; s < 2; ++s)
        bx[et][s] = fragld(xb, e * 64 + s * 32 + 8 * gq);
    } else {
      const float* px = xg + (size_t)e * 64 + 8 * gq;
#pragma unroll
      for (int s = 0; s < 2; ++s) {
        float4 u0 = *(const float4*)(px + s * 32);
        float4 u1 = *(const float4*)(px + s * 32 + 4);
        BF8 t;
        t.u[0]=f2bf(u0.x); t.u[1]=f2bf(u0.y); t.u[2]=f2bf(u0.z); t.u[3]=f2bf(u0.w);
        t.u[4]=f2bf(u1.x); t.u[5]=f2bf(u1.y); t.u[6]=f2bf(u1.z); t.u[7]=f2bf(u1.w);
        bx[et][s] = t.b;
      }
    }
  }

  __syncthreads();

  f32x4 acc[8][2];
  const f32x4 zero4 = {0.f, 0.f, 0.f, 0.f};

  // LN + SiLU in-place on acc. Lane holds h[f = 16t+4gq+j] of edge (et,l15).
  auto ln_silu = [&](int pb) {
#pragma unroll
    for (int t = 0; t < 8; ++t) {
      float4 bb = *(const float4*)&prm[pb + 16 * t + 4 * gq];
#pragma unroll
      for (int et = 0; et < 2; ++et)
#pragma unroll
        for (int j = 0; j < 4; ++j) acc[t][et][j] += ((const float*)&bb)[j];
    }
    float mu[2], rs[2];
#pragma unroll
    for (int et = 0; et < 2; ++et) {
      float sm = 0.f, sq = 0.f;
#pragma unroll
      for (int t = 0; t < 8; ++t)
#pragma unroll
        for (int j = 0; j < 4; ++j) { float v = acc[t][et][j]; sm += v; sq += v * v; }
      sm += __shfl_xor(sm, 16); sq += __shfl_xor(sq, 16);
      sm += __shfl_xor(sm, 32); sq += __shfl_xor(sq, 32);
      float m   = sm * (1.f / 128.f);
      float var = sq * (1.f / 128.f) - m * m;
      mu[et] = m;
      rs[et] = __builtin_amdgcn_rsqf(var + 1e-5f);
    }
#pragma unroll
    for (int t = 0; t < 8; ++t) {
      float4 gg = *(const float4*)&prm[pb + 128 + 16 * t + 4 * gq];
      float4 be = *(const float4*)&prm[pb + 256 + 16 * t + 4 * gq];
#pragma unroll
      for (int et = 0; et < 2; ++et)
#pragma unroll
        for (int j = 0; j < 4; ++j) {
          float v = (acc[t][et][j] - mu[et]) * rs[et];
          v = v * ((const float*)&gg)[j] + ((const float*)&be)[j];
          v = v * __builtin_amdgcn_rcpf(1.f + __expf(-v));
          acc[t][et][j] = v;
        }
    }
  };

  // D-layout -> B-fragment relayout through per-wave LDS scratch.
  // Wave wv owns rows [wv*16, wv*16+16) of act (row stride 40 elems = 80 B,
  // so b128 reads are 16B-aligned and banks are 2-way (free)).
  // Round (et,s): lanes write their f in [32s,32s+32) of the 16 et-edges
  // (row = wv*16 + l15 when the lane's edge is 16et+l15 -- every lane's
  // 4gq-offset covers distinct cols), then each lane b128-reads
  // act[row][8gq..8gq+7] = act1[edge][32s+8gq+j'] -> B-fragment.
  unsigned short* abase = act + (wv * 16 + l15) * 40;
  auto relayout = [&](bf16x8 (&bfr)[2][4]) {
#pragma unroll
    for (int et = 0; et < 2; ++et) {
#pragma unroll
      for (int s = 0; s < 4; ++s) {
#pragma unroll
        for (int b = 0; b < 2; ++b) {
          int t = 2 * s + b;
          unsigned* p = (unsigned*)(abase + 16 * b + 4 * gq);
          p[0] = pack2(acc[t][et][0], acc[t][et][1]);
          p[1] = pack2(acc[t][et][2], acc[t][et][3]);
        }
        asm volatile("s_waitcnt lgkmcnt(0)" ::: "memory");
        __builtin_amdgcn_sched_barrier(0);
        bfr[et][s] = fragld(act, (wv * 16 + l15) * 40 + 8 * gq);
        asm volatile("s_waitcnt lgkmcnt(0)" ::: "memory");   // read done before next round's writes
        __builtin_amdgcn_sched_barrier(0);
      }
    }
  };

  // ---- layer 1: D1[h][edge] = W1 . x^T ----
#pragma unroll
  for (int t = 0; t < 8; ++t)
#pragma unroll
    for (int et = 0; et < 2; ++et) acc[t][et] = zero4;
#pragma unroll
  for (int s = 0; s < 2; ++s)
#pragma unroll
    for (int t = 0; t < 8; ++t) {
      bf16x8 a = fragld(wsm, sidx(t * 16 + l15, s * 32 + 8 * gq, 64));
      acc[t][0] = __builtin_amdgcn_mfma_f32_16x16x32_bf16(a, bx[0][s], acc[t][0], 0, 0, 0);
      acc[t][1] = __builtin_amdgcn_mfma_f32_16x16x32_bf16(a, bx[1][s], acc[t][1], 0, 0, 0);
    }
  ln_silu(0);

  bf16x8 bfr[2][4];
  relayout(bfr);

  // ---- layer 2: D2[k][edge] = W2 . act^T ----
#pragma unroll
  for (int t = 0; t < 8; ++t)
#pragma unroll
    for (int et = 0; et < 2; ++et) acc[t][et] = zero4;
#pragma unroll
  for (int s = 0; s < 4; ++s)
#pragma unroll
    for (int t = 0; t < 8; ++t) {
      bf16x8 a = fragld(wsm + 8192, sidx(t * 16 + l15, s * 32 + 8 * gq, 128));
      acc[t][0] = __builtin_amdgcn_mfma_f32_16x16x32_bf16(a, bfr[0][s], acc[t][0], 0, 0, 0);
      acc[t][1] = __builtin_amdgcn_mfma_f32_16x16x32_bf16(a, bfr[1][s], acc[t][1], 0, 0, 0);
    }
  ln_silu(384);
  relayout(bfr);

  // ---- layer 3: D3[o][edge] = W3 . act2^T, + b3, store ----
  f32x4 a3[4][2];
#pragma unroll
  for (int t = 0; t < 4; ++t)
#pragma unroll
    for (int et = 0; et < 2; ++et) a3[t][et] = zero4;
#pragma unroll
  for (int s = 0; s < 4; ++s)
#pragma unroll
    for (int t = 0; t < 4; ++t) {
      bf16x8 a = fragld(wsm + 24576, sidx(t * 16 + l15, s * 32 + 8 * gq, 128));
      a3[t][0] = __builtin_amdgcn_mfma_f32_16x16x32_bf16(a, bfr[0][s], a3[t][0], 0, 0, 0);
      a3[t][1] = __builtin_amdgcn_mfma_f32_16x16x32_bf16(a, bfr[1][s], a3[t][1], 0, 0, 0);
    }
  // lane holds out[o = 16t+4gq+j][edge = l15+16et]
#pragma unroll
  for (int et = 0; et < 2; ++et) {
    int e = e0 + wrow + 16 * et + l15;
    if (e < E_TOT) {
      float* po = outp + ((size_t)n * E_TOT + e) * 64;
#pragma unroll
      for (int t = 0; t < 4; ++t) {
        float4 bb = *(const float4*)&prm[768 + 16 * t + 4 * gq];
        float4 o;
        o.x = a3[t][et][0] + bb.x;
        o.y = a3[t][et][1] + bb.y;
        o.z = a3[t][et][2] + bb.z;
        o.w = a3[t][et][3] + bb.w;
        *(float4*)(po + 16 * t + 4 * gq) = o;
      }
    }
  }
}

extern "C" void kernel_launch(void* const* d_in, const int* in_sizes, int n_in,
                              void* d_out, int out_size, void* d_ws, size_t ws_size,
                              hipStream_t stream) {
  (void)in_sizes; (void)n_in; (void)out_size;
  const float* xg   = (const float*)d_in[0];
  const float* W1c  = (const float*)d_in[1];
  const float* b1c  = (const float*)d_in[2];
  const float* g1p  = (const float*)d_in[3];
  const float* bt1p = (const float*)d_in[4];
  const float* W2p  = (const float*)d_in[5];
  const float* b2p  = (const float*)d_in[6];
  const float* g2p  = (const float*)d_in[7];
  const float* bt2p = (const float*)d_in[8];
  const float* W3p  = (const float*)d_in[9];
  const float* b3p  = (const float*)d_in[10];
  float* outp = (float*)d_out;

  const size_t WS_W = (size_t)NEXP * 32768 * sizeof(unsigned short);  // 512 KB
  const size_t WS_X = (size_t)E_TOT * 64 * sizeof(unsigned short);    // 12.8 MB
  const bool usews = ws_size >= WS_W + WS_X;

  dim3 grid(NEXP * NTILE, 1, 1);
  dim3 block(512, 1, 1);

  if (usews) {
    unsigned short* wsW = (unsigned short*)d_ws;
    unsigned short* xb  = wsW + (size_t)NEXP * 32768;
    k_conv_w<<<1024, 256, 0, stream>>>(W1c, W2p, W3p, wsW);
    k_conv_x<<<3125, 256, 0, stream>>>(xg, xb);
    k_main<true><<<grid, block, 0, stream>>>(wsW, xb, xg, W1c, b1c, g1p, bt1p,
                                             W2p, b2p, g2p, bt2p, W3p, b3p, outp);
  } else {
    k_main<false><<<grid, block, 0, stream>>>(nullptr, nullptr, xg, W1c, b1c, g1p, bt1p,
                                              W2p, b2p, g2p, bt2p, W3p, b3p, outp);
  }
}

// Round 6
// 753.441 us; speedup vs baseline: 1.0133x; 1.0133x over previous
//
#include <hip/hip_runtime.h>

#define NEXP 8
#define E_TOT 100000
#define NTILE 391  // ceil(E/256)

typedef __bf16 bf16x8 __attribute__((ext_vector_type(8)));
typedef float f32x4 __attribute__((ext_vector_type(4)));
typedef unsigned short u16x8 __attribute__((ext_vector_type(8)));

union BF8 { u16x8 u; bf16x8 b; };

__device__ __forceinline__ unsigned short f2bf(float f) {
  unsigned int u = __float_as_uint(f);
  u += 0x7fffu + ((u >> 16) & 1u);           // RNE
  return (unsigned short)(u >> 16);
}

// RNE pack of two floats into one u32 of 2xbf16 (lo in [15:0], hi in [31:16]).
__device__ __forceinline__ unsigned pack2(float lo, float hi) {
  return (unsigned)f2bf(lo) | ((unsigned)f2bf(hi) << 16);
}

// XOR-swizzled element index: row r, col c, row stride (elems).
__device__ __forceinline__ int sidx(int r, int c, int stride) {
  return r * stride + (c ^ ((r & 7) << 3));
}

__device__ __forceinline__ bf16x8 fragld(const unsigned short* a, int off) {
  BF8 t;
  t.u = *(const u16x8*)(a + off);
  return t.b;
}

__device__ __forceinline__ void stage8(unsigned short* dst, const float* src) {
  float4 a = *(const float4*)(src);
  float4 b = *(const float4*)(src + 4);
  BF8 t;
  t.u[0]=f2bf(a.x); t.u[1]=f2bf(a.y); t.u[2]=f2bf(a.z); t.u[3]=f2bf(a.w);
  t.u[4]=f2bf(b.x); t.u[5]=f2bf(b.y); t.u[6]=f2bf(b.z); t.u[7]=f2bf(b.w);
  *(u16x8*)dst = t.u;
}

// ---- pre-kernel: weights fp32 -> bf16, PRE-SWIZZLED to LDS-linear order ----
__global__ void k_conv_w(const float* __restrict__ W1c, const float* __restrict__ W2p,
                         const float* __restrict__ W3p, unsigned short* __restrict__ wsW) {
  int gid = blockIdx.x * 256 + threadIdx.x;     // [0, 262144)
  int n = gid >> 15, p = gid & 32767;
  float v;
  if (p < 8192) {
    int r = p >> 6, cs = p & 63;
    v = W1c[(size_t)n * 8192 + r * 64 + (cs ^ ((r & 7) << 3))];
  } else if (p < 24576) {
    int q = p - 8192; int r = q >> 7, cs = q & 127;
    v = W2p[(size_t)n * 16384 + r * 128 + (cs ^ ((r & 7) << 3))];
  } else {
    int q = p - 24576; int r = q >> 7, cs = q & 127;
    v = W3p[(size_t)n * 8192 + r * 128 + (cs ^ ((r & 7) << 3))];
  }
  wsW[gid] = f2bf(v);
}

// ---- pre-kernel: x fp32 -> bf16 ----
__global__ void k_conv_x(const float* __restrict__ xg, unsigned short* __restrict__ xb) {
  int gid = blockIdx.x * 256 + threadIdx.x;     // 800000 threads, 8 elems each
  const float* s = xg + (size_t)gid * 8;
  stage8(xb + (size_t)gid * 8, s);
}

// ---- main kernel: swapped-operand (D = W . x^T), activations in registers,
//      D->B relayout via small per-wave LDS roundtrip ----
template <bool USEWS>
__global__ __launch_bounds__(512, 4) void k_main(
    const unsigned short* __restrict__ wsW, const unsigned short* __restrict__ xb,
    const float* __restrict__ xg,
    const float* __restrict__ W1c, const float* __restrict__ b1c,
    const float* __restrict__ g1p, const float* __restrict__ bt1p,
    const float* __restrict__ W2p, const float* __restrict__ b2p,
    const float* __restrict__ g2p, const float* __restrict__ bt2p,
    const float* __restrict__ W3p, const float* __restrict__ b3p,
    float* __restrict__ outp)
{
  __shared__ __attribute__((aligned(16))) unsigned short wsm[32768];  // 64 KB weights (swizzled)
  __shared__ __attribute__((aligned(16))) unsigned short act[128*40]; // 10 KB relayout scratch
  __shared__ __attribute__((aligned(16))) float prm[832];             // LN params + b3

  // bijective remap: flat bid -> (tile, expert); each XCD (bid%8) owns a
  // contiguous tile range with all 8 experts -> x slab fetched once/XCD
  const int bid = blockIdx.x;
  const int g_  = (bid & 7) * NTILE + (bid >> 3);
  const int tile = g_ >> 3;
  const int n    = g_ & 7;
  const int e0   = tile * 256;

  const int tid  = threadIdx.x;
  const int lane = tid & 63;
  const int wv   = tid >> 6;
  const int l15  = lane & 15;
  const int gq   = lane >> 4;          // 0..3
  const int wrow = wv * 32;            // wave's 32 edges within tile

  // ---- stage weights into LDS ----
  if (USEWS) {
    const unsigned short* src = wsW + (size_t)n * 32768;
#pragma unroll
    for (int i = 0; i < 8; ++i) {
      int c8 = tid + i * 512;          // u16x8 chunk id, 4096 total
      *(u16x8*)&wsm[c8 * 8] = *(const u16x8*)&src[c8 * 8];
    }
  } else {
    const float* s1 = W1c + (size_t)n * 8192;
#pragma unroll
    for (int i = 0; i < 2; ++i) {
      int c = tid + i * 512; int r = c >> 3, co = (c & 7) << 3;
      stage8(&wsm[sidx(r, co, 64)], s1 + r * 64 + co);
    }
    const float* s2 = W2p + (size_t)n * 16384;
#pragma unroll
    for (int i = 0; i < 4; ++i) {
      int c = tid + i * 512; int r = c >> 4, co = (c & 15) << 3;
      stage8(&wsm[8192 + sidx(r, co, 128)], s2 + r * 128 + co);
    }
    const float* s3 = W3p + (size_t)n * 8192;
#pragma unroll
    for (int i = 0; i < 2; ++i) {
      int c = tid + i * 512; int r = c >> 4, co = (c & 15) << 3;
      stage8(&wsm[24576 + sidx(r, co, 128)], s3 + r * 128 + co);
    }
  }
  // ---- stage LN params (832 slots, 512 threads -> strided loop) ----
  for (int i = tid; i < 832; i += 512) {
    int grp = i >> 7, f = i & 127;
    float v;
    switch (grp) {
      case 0: v = b1c [n * 128 + f]; break;
      case 1: v = g1p [n * 128 + f]; break;
      case 2: v = bt1p[n * 128 + f]; break;
      case 3: v = b2p [n * 128 + f]; break;
      case 4: v = g2p [n * 128 + f]; break;
      case 5: v = bt2p[n * 128 + f]; break;
      default: v = b3p[n * 64 + f]; break;   // i in 768..831, f = i-768
    }
    prm[i] = v;
  }

  // ---- x B-fragments: lane holds x[edge = l15+16et][d = 8gq+j+32s] ----
  bf16x8 bx[2][2];
#pragma unroll
  for (int et = 0; et < 2; ++et) {
    int e = e0 + wrow + 16 * et + l15;
    if (e >= E_TOT) e = E_TOT - 1;
    if (USEWS) {
#pragma unroll
      for (int s = 0; s < 2; ++s)
        bx[et][s] = fragld(xb, e * 64 + s * 32 + 8 * gq);
    } else {
      const float* px = xg + (size_t)e * 64 + 8 * gq;
#pragma unroll
      for (int s = 0; s < 2; ++s) {
        float4 u0 = *(const float4*)(px + s * 32);
        float4 u1 = *(const float4*)(px + s * 32 + 4);
        BF8 t;
        t.u[0]=f2bf(u0.x); t.u[1]=f2bf(u0.y); t.u[2]=f2bf(u0.z); t.u[3]=f2bf(u0.w);
        t.u[4]=f2bf(u1.x); t.u[5]=f2bf(u1.y); t.u[6]=f2bf(u1.z); t.u[7]=f2bf(u1.w);
        bx[et][s] = t.b;
      }
    }
  }

  __syncthreads();

  f32x4 acc[8][2];
  const f32x4 zero4 = {0.f, 0.f, 0.f, 0.f};

  // LN + SiLU in-place on acc. Lane holds h[f = 16t+4gq+j] of edge (et,l15).
  auto ln_silu = [&](int pb) {
#pragma unroll
    for (int t = 0; t < 8; ++t) {
      float4 bb = *(const float4*)&prm[pb + 16 * t + 4 * gq];
#pragma unroll
      for (int et = 0; et < 2; ++et)
#pragma unroll
        for (int j = 0; j < 4; ++j) acc[t][et][j] += ((const float*)&bb)[j];
    }
    float mu[2], rs[2];
#pragma unroll
    for (int et = 0; et < 2; ++et) {
      float sm = 0.f, sq = 0.f;
#pragma unroll
      for (int t = 0; t < 8; ++t)
#pragma unroll
        for (int j = 0; j < 4; ++j) { float v = acc[t][et][j]; sm += v; sq += v * v; }
      sm += __shfl_xor(sm, 16); sq += __shfl_xor(sq, 16);
      sm += __shfl_xor(sm, 32); sq += __shfl_xor(sq, 32);
      float m   = sm * (1.f / 128.f);
      float var = sq * (1.f / 128.f) - m * m;
      mu[et] = m;
      rs[et] = __builtin_amdgcn_rsqf(var + 1e-5f);
    }
#pragma unroll
    for (int t = 0; t < 8; ++t) {
      float4 gg = *(const float4*)&prm[pb + 128 + 16 * t + 4 * gq];
      float4 be = *(const float4*)&prm[pb + 256 + 16 * t + 4 * gq];
#pragma unroll
      for (int et = 0; et < 2; ++et)
#pragma unroll
        for (int j = 0; j < 4; ++j) {
          float v = (acc[t][et][j] - mu[et]) * rs[et];
          v = v * ((const float*)&gg)[j] + ((const float*)&be)[j];
          v = v * __builtin_amdgcn_rcpf(1.f + __expf(-v));
          acc[t][et][j] = v;
        }
    }
  };

  // D-layout -> B-fragment relayout through per-wave LDS scratch.
  // Wave wv owns rows [wv*16, wv*16+16) of act (row stride 40 elems = 80 B:
  // b128 reads 16B-aligned, banks 2-way = free).
  // Round (et,s): lane (l15,gq) writes features f=32s+c (c=16b+4gq+j) of edge
  // 16et+l15 at cols c of row wv*16+l15; reads back cols 8gq..8gq+7 = the
  // B-fragment (et,s). Intra-wave LDS ops execute in order (same-wave DS pipe);
  // wave_barrier() is a zero-cost compiler code-motion fence only.
  // NOTE R5->R6: asm lgkmcnt+sched_barrier(0) here forced the allocator to
  // spill acc to scratch (VGPR 60, 3.5 GB spill traffic, 763 us). Do NOT
  // reintroduce memory-clobber asm inside this loop.
  unsigned short* abase = act + (wv * 16 + l15) * 40;
  auto relayout = [&](bf16x8 (&bfr)[2][4]) {
#pragma unroll
    for (int et = 0; et < 2; ++et) {
#pragma unroll
      for (int s = 0; s < 4; ++s) {
#pragma unroll
        for (int b = 0; b < 2; ++b) {
          int t = 2 * s + b;
          unsigned* p = (unsigned*)(abase + 16 * b + 4 * gq);
          p[0] = pack2(acc[t][et][0], acc[t][et][1]);
          p[1] = pack2(acc[t][et][2], acc[t][et][3]);
        }
        __builtin_amdgcn_wave_barrier();
        bfr[et][s] = fragld(act, (wv * 16 + l15) * 40 + 8 * gq);
        __builtin_amdgcn_wave_barrier();   // WAR fence vs next round's writes
      }
    }
  };

  // ---- layer 1: D1[h][edge] = W1 . x^T ----
#pragma unroll
  for (int t = 0; t < 8; ++t)
#pragma unroll
    for (int et = 0; et < 2; ++et) acc[t][et] = zero4;
#pragma unroll
  for (int s = 0; s < 2; ++s)
#pragma unroll
    for (int t = 0; t < 8; ++t) {
      bf16x8 a = fragld(wsm, sidx(t * 16 + l15, s * 32 + 8 * gq, 64));
      acc[t][0] = __builtin_amdgcn_mfma_f32_16x16x32_bf16(a, bx[0][s], acc[t][0], 0, 0, 0);
      acc[t][1] = __builtin_amdgcn_mfma_f32_16x16x32_bf16(a, bx[1][s], acc[t][1], 0, 0, 0);
    }
  ln_silu(0);

  bf16x8 bfr[2][4];
  relayout(bfr);

  // ---- layer 2: D2[k][edge] = W2 . act^T ----
#pragma unroll
  for (int t = 0; t < 8; ++t)
#pragma unroll
    for (int et = 0; et < 2; ++et) acc[t][et] = zero4;
#pragma unroll
  for (int s = 0; s < 4; ++s)
#pragma unroll
    for (int t = 0; t < 8; ++t) {
      bf16x8 a = fragld(wsm + 8192, sidx(t * 16 + l15, s * 32 + 8 * gq, 128));
      acc[t][0] = __builtin_amdgcn_mfma_f32_16x16x32_bf16(a, bfr[0][s], acc[t][0], 0, 0, 0);
      acc[t][1] = __builtin_amdgcn_mfma_f32_16x16x32_bf16(a, bfr[1][s], acc[t][1], 0, 0, 0);
    }
  ln_silu(384);
  relayout(bfr);

  // ---- layer 3: D3[o][edge] = W3 . act2^T, + b3, store ----
  f32x4 a3[4][2];
#pragma unroll
  for (int t = 0; t < 4; ++t)
#pragma unroll
    for (int et = 0; et < 2; ++et) a3[t][et] = zero4;
#pragma unroll
  for (int s = 0; s < 4; ++s)
#pragma unroll
    for (int t = 0; t < 4; ++t) {
      bf16x8 a = fragld(wsm + 24576, sidx(t * 16 + l15, s * 32 + 8 * gq, 128));
      a3[t][0] = __builtin_amdgcn_mfma_f32_16x16x32_bf16(a, bfr[0][s], a3[t][0], 0, 0, 0);
      a3[t][1] = __builtin_amdgcn_mfma_f32_16x16x32_bf16(a, bfr[1][s], a3[t][1], 0, 0, 0);
    }
  // lane holds out[o = 16t+4gq+j][edge = l15+16et]
#pragma unroll
  for (int et = 0; et < 2; ++et) {
    int e = e0 + wrow + 16 * et + l15;
    if (e < E_TOT) {
      float* po = outp + ((size_t)n * E_TOT + e) * 64;
#pragma unroll
      for (int t = 0; t < 4; ++t) {
        float4 bb = *(const float4*)&prm[768 + 16 * t + 4 * gq];
        float4 o;
        o.x = a3[t][et][0] + bb.x;
        o.y = a3[t][et][1] + bb.y;
        o.z = a3[t][et][2] + bb.z;
        o.w = a3[t][et][3] + bb.w;
        *(float4*)(po + 16 * t + 4 * gq) = o;
      }
    }
  }
}

extern "C" void kernel_launch(void* const* d_in, const int* in_sizes, int n_in,
                              void* d_out, int out_size, void* d_ws, size_t ws_size,
                              hipStream_t stream) {
  (void)in_sizes; (void)n_in; (void)out_size;
  const float* xg   = (const float*)d_in[0];
  const float* W1c  = (const float*)d_in[1];
  const float* b1c  = (const float*)d_in[2];
  const float* g1p  = (const float*)d_in[3];
  const float* bt1p = (const float*)d_in[4];
  const float* W2p  = (const float*)d_in[5];
  const float* b2p  = (const float*)d_in[6];
  const float* g2p  = (const float*)d_in[7];
  const float* bt2p = (const float*)d_in[8];
  const float* W3p  = (const float*)d_in[9];
  const float* b3p  = (const float*)d_in[10];
  float* outp = (float*)d_out;

  const size_t WS_W = (size_t)NEXP * 32768 * sizeof(unsigned short);  // 512 KB
  const size_t WS_X = (size_t)E_TOT * 64 * sizeof(unsigned short);    // 12.8 MB
  const bool usews = ws_size >= WS_W + WS_X;

  dim3 grid(NEXP * NTILE, 1, 1);
  dim3 block(512, 1, 1);

  if (usews) {
    unsigned short* wsW = (unsigned short*)d_ws;
    unsigned short* xb  = wsW + (size_t)NEXP * 32768;
    k_conv_w<<<1024, 256, 0, stream>>>(W1c, W2p, W3p, wsW);
    k_conv_x<<<3125, 256, 0, stream>>>(xg, xb);
    k_main<true><<<grid, block, 0, stream>>>(wsW, xb, xg, W1c, b1c, g1p, bt1p,
                                             W2p, b2p, g2p, bt2p, W3p, b3p, outp);
  } else {
    k_main<false><<<grid, block, 0, stream>>>(nullptr, nullptr, xg, W1c, b1c, g1p, bt1p,
                                              W2p, b2p, g2p, bt2p, W3p, b3p, outp);
  }
}

// Round 9
// 190.584 us; speedup vs baseline: 4.0057x; 3.9533x over previous
//
#include <hip/hip_runtime.h>

#define NEXP 8
#define E_TOT 100000
#define EPB 128                 // edges per block (4 waves x 32)
#define NTILE 782               // ceil(E/EPB)

typedef __bf16 bf16x8 __attribute__((ext_vector_type(8)));
typedef float f32x4 __attribute__((ext_vector_type(4)));
typedef unsigned short u16x8 __attribute__((ext_vector_type(8)));

union BF8 { u16x8 u; bf16x8 b; };

__device__ __forceinline__ unsigned short f2bf(float f) {
  unsigned int u = __float_as_uint(f);
  u += 0x7fffu + ((u >> 16) & 1u);           // RNE
  return (unsigned short)(u >> 16);
}

// XOR-swizzled element index: row r, col c, row stride (elems). (R1-validated)
__device__ __forceinline__ int sidx(int r, int c, int stride) {
  return r * stride + (c ^ ((r & 7) << 3));
}

__device__ __forceinline__ bf16x8 fragld(const unsigned short* a, int off) {
  BF8 t;
  t.u = *(const u16x8*)(a + off);
  return t.b;
}

__device__ __forceinline__ bf16x8 frag_f32(const float* s) {
  float4 u0 = *(const float4*)s;
  float4 u1 = *(const float4*)(s + 4);
  BF8 t;
  t.u[0]=f2bf(u0.x); t.u[1]=f2bf(u0.y); t.u[2]=f2bf(u0.z); t.u[3]=f2bf(u0.w);
  t.u[4]=f2bf(u1.x); t.u[5]=f2bf(u1.y); t.u[6]=f2bf(u1.z); t.u[7]=f2bf(u1.w);
  return t.b;
}

// ---- pre-kernel: weights fp32 -> bf16 in FRAGMENT-CONTIGUOUS layout ----
// Per expert n (32768 u16): L1 [0,8192) 16 frags, L2 [8192,24576) 32 frags,
// L3 [24576,32768) 16 frags. Each frag = 512 u16 = 64 lanes x 8 elems.
// Frag (t,s), lane (l15,gq), elem j holds W[16t+l15][32s+8gq+j]  (B-operand).
__global__ void k_conv_w(const float* __restrict__ W1c, const float* __restrict__ W2p,
                         const float* __restrict__ W3p, unsigned short* __restrict__ wsW) {
  int gid = blockIdx.x * 256 + threadIdx.x;     // [0, 262144)
  int n = gid >> 15, p = gid & 32767;
  int idx, frag, t, s;
  const float* base;
  int K;
  if (p < 8192)       { idx = p;         frag = idx >> 9; t = frag >> 1; s = frag & 1;
                        base = W1c + (size_t)n * 8192;  K = 64; }
  else if (p < 24576) { idx = p - 8192;  frag = idx >> 9; t = frag >> 2; s = frag & 3;
                        base = W2p + (size_t)n * 16384; K = 128; }
  else                { idx = p - 24576; frag = idx >> 9; t = frag >> 2; s = frag & 3;
                        base = W3p + (size_t)n * 8192;  K = 128; }
  int r = idx & 511, lane = r >> 3, j = r & 7;
  int l15 = lane & 15, gq = lane >> 4;
  wsW[gid] = f2bf(base[(16 * t + l15) * K + 32 * s + 8 * gq + j]);
}

// ---- pre-kernel: x fp32 -> bf16 ----
__global__ void k_conv_x(const float* __restrict__ xg, unsigned short* __restrict__ xb) {
  int gid = blockIdx.x * 256 + threadIdx.x;     // 800000 threads, 8 elems each
  const float* s = xg + (size_t)gid * 8;
  BF8 t;
  float4 a = *(const float4*)s, b = *(const float4*)(s + 4);
  t.u[0]=f2bf(a.x); t.u[1]=f2bf(a.y); t.u[2]=f2bf(a.z); t.u[3]=f2bf(a.w);
  t.u[4]=f2bf(b.x); t.u[5]=f2bf(b.y); t.u[6]=f2bf(b.z); t.u[7]=f2bf(b.w);
  *(u16x8*)(xb + (size_t)gid * 8) = t.u;
}

// ---- main kernel: R1 structure (D = x . W^T per layer), weights from L2,
//      activations through sidx'd hs (per-wave slab, no barrier: R1-validated).
// R2-R8 lessons kept: prm staged via strided loop; no wave_barrier /
// sched_barrier / memory-clobber asm; no tight launch-bounds VGPR cap.
template <bool USEWS>
__global__ __launch_bounds__(256, 2) void k_main(
    const unsigned short* __restrict__ wsW, const unsigned short* __restrict__ xb,
    const float* __restrict__ xg,
    const float* __restrict__ W1c, const float* __restrict__ b1c,
    const float* __restrict__ g1p, const float* __restrict__ bt1p,
    const float* __restrict__ W2p, const float* __restrict__ b2p,
    const float* __restrict__ g2p, const float* __restrict__ bt2p,
    const float* __restrict__ W3p, const float* __restrict__ b3p,
    float* __restrict__ outp)
{
  __shared__ __attribute__((aligned(16))) unsigned short hs[EPB * 128]; // 32 KB activations
  __shared__ __attribute__((aligned(16))) float prm[832];               // LN params + b3

  // bijective XCD remap (6256 = 8 * 782 exact): each XCD owns a contiguous
  // tile range with all 8 experts -> x slab + weight set stay L2-hot.
  const int bid = blockIdx.x;
  const int g_  = (bid & 7) * NTILE + (bid >> 3);
  const int tile = g_ >> 3;
  const int n    = g_ & 7;
  const int e0   = tile * EPB;

  const int tid  = threadIdx.x;
  const int lane = tid & 63;
  const int wv   = tid >> 6;           // 0..3
  const int l15  = lane & 15;
  const int gq   = lane >> 4;          // 0..3
  const int wrow = wv * 32;            // wave's 32 edges within tile

  // ---- stage LN params (832 slots, 256 threads -> strided loop) ----
  for (int i = tid; i < 832; i += 256) {
    int grp = i >> 7, f = i & 127;
    float v;
    switch (grp) {
      case 0: v = b1c [n * 128 + f]; break;
      case 1: v = g1p [n * 128 + f]; break;
      case 2: v = bt1p[n * 128 + f]; break;
      case 3: v = b2p [n * 128 + f]; break;
      case 4: v = g2p [n * 128 + f]; break;
      case 5: v = bt2p[n * 128 + f]; break;
      default: v = b3p[n * 64 + f]; break;   // i in 768..831
    }
    prm[i] = v;
  }

  // ---- x A-fragments: lane holds x[edge = e0+wrow+16rt+l15][d = 32s+8gq+j] ----
  bf16x8 ax[2][2];
#pragma unroll
  for (int rt = 0; rt < 2; ++rt) {
    int e = e0 + wrow + 16 * rt + l15;
    if (e >= E_TOT) e = E_TOT - 1;               // clamp; garbage never stored
    if (USEWS) {
#pragma unroll
      for (int s = 0; s < 2; ++s)
        ax[rt][s] = fragld(xb, e * 64 + s * 32 + 8 * gq);
    } else {
#pragma unroll
      for (int s = 0; s < 2; ++s)
        ax[rt][s] = frag_f32(xg + (size_t)e * 64 + s * 32 + 8 * gq);
    }
  }

  // weight fragment bases (fragment-contiguous bf16) or fp32 fallback
  const unsigned short* wf1 = wsW + (size_t)n * 32768;
  const unsigned short* wf2 = wf1 + 8192;
  const unsigned short* wf3 = wf1 + 24576;
  const float* W1n = W1c + (size_t)n * 8192;
  const float* W2n = W2p + (size_t)n * 16384;
  const float* W3n = W3p + (size_t)n * 8192;

  // B-fragment of W_l for frag (t,s): lane (l15,gq) elem j = W[16t+l15][32s+8gq+j]
  auto wfragA = [&](const unsigned short* wf, const float* Wn, int nfs, int t, int s, int K) {
    if (USEWS) return fragld(wf, ((t * nfs + s) << 9) + (lane << 3));
    return frag_f32(Wn + (16 * t + l15) * K + 32 * s + 8 * gq);
  };

  __syncthreads();   // prm ready (hs is per-wave, needs no barrier)

  f32x4 acc[2][8];
  const f32x4 zero4 = {0.f, 0.f, 0.f, 0.f};

  // LN + SiLU + bf16 store of the wave's 32x128 slab into hs. (R1-validated)
  // D layout: col = feature 16ct+l15, row = edge 4gq+j (+16rt).
  auto ln_silu_store = [&](f32x4 (&A)[2][8], int pb) {
#pragma unroll
    for (int rt = 0; rt < 2; ++rt) {
      float sm[4] = {0.f,0.f,0.f,0.f}, sq[4] = {0.f,0.f,0.f,0.f};
#pragma unroll
      for (int ct = 0; ct < 8; ++ct) {
        float bv = prm[pb + 16 * ct + l15];
#pragma unroll
        for (int j = 0; j < 4; ++j) {
          float v = A[rt][ct][j] + bv;
          A[rt][ct][j] = v;
          sm[j] += v;
          sq[j] += v * v;
        }
      }
#pragma unroll
      for (int m = 1; m <= 8; m <<= 1) {
#pragma unroll
        for (int j = 0; j < 4; ++j) {
          sm[j] += __shfl_xor(sm[j], m);
          sq[j] += __shfl_xor(sq[j], m);
        }
      }
#pragma unroll
      for (int j = 0; j < 4; ++j) {
        float mu  = sm[j] * (1.f / 128.f);
        float var = sq[j] * (1.f / 128.f) - mu * mu;
        sm[j] = mu;
        sq[j] = __builtin_amdgcn_rsqf(var + 1e-5f);
      }
      int r0 = wrow + rt * 16 + 4 * gq;
#pragma unroll
      for (int ct = 0; ct < 8; ++ct) {
        float gv  = prm[pb + 128 + 16 * ct + l15];
        float btv = prm[pb + 256 + 16 * ct + l15];
#pragma unroll
        for (int j = 0; j < 4; ++j) {
          float v = (A[rt][ct][j] - sm[j]) * sq[j] * gv + btv;
          v = v * __builtin_amdgcn_rcpf(1.f + __expf(-v));   // silu
          hs[sidx(r0 + j, ct * 16 + l15, 128)] = f2bf(v);
        }
      }
    }
  };

  // ---- layer 1: [32 x 64] @ [64 x 128] ----
#pragma unroll
  for (int rt = 0; rt < 2; ++rt)
#pragma unroll
    for (int ct = 0; ct < 8; ++ct) acc[rt][ct] = zero4;
#pragma unroll
  for (int s = 0; s < 2; ++s) {
#pragma unroll
    for (int ct = 0; ct < 8; ++ct) {
      bf16x8 b = wfragA(wf1, W1n, 2, ct, s, 64);
      acc[0][ct] = __builtin_amdgcn_mfma_f32_16x16x32_bf16(ax[0][s], b, acc[0][ct], 0, 0, 0);
      acc[1][ct] = __builtin_amdgcn_mfma_f32_16x16x32_bf16(ax[1][s], b, acc[1][ct], 0, 0, 0);
    }
  }
  ln_silu_store(acc, 0);

  // ---- layer 2: [32 x 128] @ [128 x 128] (reads own slab only; no barrier) ----
#pragma unroll
  for (int rt = 0; rt < 2; ++rt)
#pragma unroll
    for (int ct = 0; ct < 8; ++ct) acc[rt][ct] = zero4;
#pragma unroll
  for (int ks = 0; ks < 4; ++ks) {
    bf16x8 a0 = fragld(hs, sidx(wrow + l15,      ks * 32 + 8 * gq, 128));
    bf16x8 a1 = fragld(hs, sidx(wrow + 16 + l15, ks * 32 + 8 * gq, 128));
#pragma unroll
    for (int ct = 0; ct < 8; ++ct) {
      bf16x8 b = wfragA(wf2, W2n, 4, ct, ks, 128);
      acc[0][ct] = __builtin_amdgcn_mfma_f32_16x16x32_bf16(a0, b, acc[0][ct], 0, 0, 0);
      acc[1][ct] = __builtin_amdgcn_mfma_f32_16x16x32_bf16(a1, b, acc[1][ct], 0, 0, 0);
    }
  }
  ln_silu_store(acc, 384);

  // ---- layer 3: [32 x 128] @ [128 x 64] + b3, store ----
  f32x4 a3[2][4];
#pragma unroll
  for (int rt = 0; rt < 2; ++rt)
#pragma unroll
    for (int ct = 0; ct < 4; ++ct) a3[rt][ct] = zero4;
#pragma unroll
  for (int ks = 0; ks < 4; ++ks) {
    bf16x8 a0 = fragld(hs, sidx(wrow + l15,      ks * 32 + 8 * gq, 128));
    bf16x8 a1 = fragld(hs, sidx(wrow + 16 + l15, ks * 32 + 8 * gq, 128));
#pragma unroll
    for (int ct = 0; ct < 4; ++ct) {
      bf16x8 b = wfragA(wf3, W3n, 4, ct, ks, 128);
      a3[0][ct] = __builtin_amdgcn_mfma_f32_16x16x32_bf16(a0, b, a3[0][ct], 0, 0, 0);
      a3[1][ct] = __builtin_amdgcn_mfma_f32_16x16x32_bf16(a1, b, a3[1][ct], 0, 0, 0);
    }
  }

  // out[n][e][d], fp32. Lanes 0..15 cover 16 consecutive d -> 64B segments.
#pragma unroll
  for (int rt = 0; rt < 2; ++rt) {
#pragma unroll
    for (int j = 0; j < 4; ++j) {
      int e = e0 + wrow + rt * 16 + 4 * gq + j;
      if (e < E_TOT) {
        float* po = outp + ((size_t)n * E_TOT + e) * 64 + l15;
#pragma unroll
        for (int ct = 0; ct < 4; ++ct)
          po[ct * 16] = a3[rt][ct][j] + prm[768 + 16 * ct + l15];
      }
    }
  }
}

extern "C" void kernel_launch(void* const* d_in, const int* in_sizes, int n_in,
                              void* d_out, int out_size, void* d_ws, size_t ws_size,
                              hipStream_t stream) {
  (void)in_sizes; (void)n_in; (void)out_size;
  const float* xg   = (const float*)d_in[0];
  const float* W1c  = (const float*)d_in[1];
  const float* b1c  = (const float*)d_in[2];
  const float* g1p  = (const float*)d_in[3];
  const float* bt1p = (const float*)d_in[4];
  const float* W2p  = (const float*)d_in[5];
  const float* b2p  = (const float*)d_in[6];
  const float* g2p  = (const float*)d_in[7];
  const float* bt2p = (const float*)d_in[8];
  const float* W3p  = (const float*)d_in[9];
  const float* b3p  = (const float*)d_in[10];
  float* outp = (float*)d_out;

  const size_t WS_W = (size_t)NEXP * 32768 * sizeof(unsigned short);  // 512 KB
  const size_t WS_X = (size_t)E_TOT * 64 * sizeof(unsigned short);    // 12.8 MB
  const bool usews = ws_size >= WS_W + WS_X;

  dim3 grid(NEXP * NTILE, 1, 1);
  dim3 block(256, 1, 1);

  if (usews) {
    unsigned short* wsW = (unsigned short*)d_ws;
    unsigned short* xb  = wsW + (size_t)NEXP * 32768;
    k_conv_w<<<1024, 256, 0, stream>>>(W1c, W2p, W3p, wsW);
    k_conv_x<<<3125, 256, 0, stream>>>(xg, xb);
    k_main<true><<<grid, block, 0, stream>>>(wsW, xb, xg, W1c, b1c, g1p, bt1p,
                                             W2p, b2p, g2p, bt2p, W3p, b3p, outp);
  } else {
    k_main<false><<<grid, block, 0, stream>>>(nullptr, nullptr, xg, W1c, b1c, g1p, bt1p,
                                              W2p, b2p, g2p, bt2p, W3p, b3p, outp);
  }
}

// Round 10
// 180.747 us; speedup vs baseline: 4.2237x; 1.0544x over previous
//
#include <hip/hip_runtime.h>

#define NEXP 8
#define E_TOT 100000
#define EPB 128                 // edges per block (4 waves x 32)
#define NTILE 782               // ceil(E/EPB)

typedef __bf16 bf16x8 __attribute__((ext_vector_type(8)));
typedef float f32x4 __attribute__((ext_vector_type(4)));
typedef unsigned short u16x8 __attribute__((ext_vector_type(8)));

union BF8 { u16x8 u; bf16x8 b; };
union BW  { __bf16 h; unsigned short u; };

__device__ __forceinline__ unsigned short f2bf(float f) {
  unsigned int u = __float_as_uint(f);
  u += 0x7fffu + ((u >> 16) & 1u);           // RNE
  return (unsigned short)(u >> 16);
}

// XOR-swizzled element index: row r, col c, row stride (elems). (R1-validated)
__device__ __forceinline__ int sidx(int r, int c, int stride) {
  return r * stride + (c ^ ((r & 7) << 3));
}

__device__ __forceinline__ bf16x8 fragld(const unsigned short* a, int off) {
  BF8 t;
  t.u = *(const u16x8*)(a + off);
  return t.b;
}

__device__ __forceinline__ bf16x8 frag_f32(const float* s) {
  float4 u0 = *(const float4*)s;
  float4 u1 = *(const float4*)(s + 4);
  BF8 t;
  t.u[0]=f2bf(u0.x); t.u[1]=f2bf(u0.y); t.u[2]=f2bf(u0.z); t.u[3]=f2bf(u0.w);
  t.u[4]=f2bf(u1.x); t.u[5]=f2bf(u1.y); t.u[6]=f2bf(u1.z); t.u[7]=f2bf(u1.w);
  return t.b;
}

// ---- pre-kernel: weights fp32 -> bf16 in FRAGMENT-CONTIGUOUS layout ----
// Per expert n (32768 u16): L1 [0,8192) 16 frags, L2 [8192,24576) 32 frags,
// L3 [24576,32768) 16 frags. Each frag = 512 u16 = 64 lanes x 8 elems.
// Frag (t,s), lane (l15,gq), elem j holds W[16t+l15][32s+8gq+j]  (B-operand).
__global__ void k_conv_w(const float* __restrict__ W1c, const float* __restrict__ W2p,
                         const float* __restrict__ W3p, unsigned short* __restrict__ wsW) {
  int gid = blockIdx.x * 256 + threadIdx.x;     // [0, 262144)
  int n = gid >> 15, p = gid & 32767;
  int idx, frag, t, s;
  const float* base;
  int K;
  if (p < 8192)       { idx = p;         frag = idx >> 9; t = frag >> 1; s = frag & 1;
                        base = W1c + (size_t)n * 8192;  K = 64; }
  else if (p < 24576) { idx = p - 8192;  frag = idx >> 9; t = frag >> 2; s = frag & 3;
                        base = W2p + (size_t)n * 16384; K = 128; }
  else                { idx = p - 24576; frag = idx >> 9; t = frag >> 2; s = frag & 3;
                        base = W3p + (size_t)n * 8192;  K = 128; }
  int r = idx & 511, lane = r >> 3, j = r & 7;
  int l15 = lane & 15, gq = lane >> 4;
  wsW[gid] = f2bf(base[(16 * t + l15) * K + 32 * s + 8 * gq + j]);
}

// ---- pre-kernel: x fp32 -> bf16 ----
__global__ void k_conv_x(const float* __restrict__ xg, unsigned short* __restrict__ xb) {
  int gid = blockIdx.x * 256 + threadIdx.x;     // 800000 threads, 8 elems each
  const float* s = xg + (size_t)gid * 8;
  BF8 t;
  float4 a = *(const float4*)s, b = *(const float4*)(s + 4);
  t.u[0]=f2bf(a.x); t.u[1]=f2bf(a.y); t.u[2]=f2bf(a.z); t.u[3]=f2bf(a.w);
  t.u[4]=f2bf(b.x); t.u[5]=f2bf(b.y); t.u[6]=f2bf(b.z); t.u[7]=f2bf(b.w);
  *(u16x8*)(xb + (size_t)gid * 8) = t.u;
}

// ---- main kernel: R1/R9 structure (D = x . W^T per layer), weights from L2,
//      activations through sidx'd hs (per-wave slab, no barrier).
// R10 changes (epilogue diet only; layouts identical to passing R9):
//  - bias folded into MFMA accumulator init (C-in = bias broadcast)
//  - epilogue sums/normalize written as f32x4 vector ops (v_pk_*_f32)
//  - hs stores use native __bf16 casts (1-inst v_cvt vs 3-inst RNE trick)
// Kept lessons: prm strided staging; no wave_barrier/sched_barrier/mem-clobber
// asm; no tight launch-bounds VGPR cap.
template <bool USEWS>
__global__ __launch_bounds__(256, 2) void k_main(
    const unsigned short* __restrict__ wsW, const unsigned short* __restrict__ xb,
    const float* __restrict__ xg,
    const float* __restrict__ W1c, const float* __restrict__ b1c,
    const float* __restrict__ g1p, const float* __restrict__ bt1p,
    const float* __restrict__ W2p, const float* __restrict__ b2p,
    const float* __restrict__ g2p, const float* __restrict__ bt2p,
    const float* __restrict__ W3p, const float* __restrict__ b3p,
    float* __restrict__ outp)
{
  __shared__ __attribute__((aligned(16))) unsigned short hs[EPB * 128]; // 32 KB activations
  __shared__ __attribute__((aligned(16))) float prm[832];               // LN params + b3

  // bijective XCD remap (6256 = 8 * 782 exact): each XCD owns a contiguous
  // tile range with all 8 experts -> x slab + weight set stay L2-hot.
  const int bid = blockIdx.x;
  const int g_  = (bid & 7) * NTILE + (bid >> 3);
  const int tile = g_ >> 3;
  const int n    = g_ & 7;
  const int e0   = tile * EPB;

  const int tid  = threadIdx.x;
  const int lane = tid & 63;
  const int wv   = tid >> 6;           // 0..3
  const int l15  = lane & 15;
  const int gq   = lane >> 4;          // 0..3
  const int wrow = wv * 32;            // wave's 32 edges within tile

  // ---- stage LN params (832 slots, 256 threads -> strided loop) ----
  for (int i = tid; i < 832; i += 256) {
    int grp = i >> 7, f = i & 127;
    float v;
    switch (grp) {
      case 0: v = b1c [n * 128 + f]; break;
      case 1: v = g1p [n * 128 + f]; break;
      case 2: v = bt1p[n * 128 + f]; break;
      case 3: v = b2p [n * 128 + f]; break;
      case 4: v = g2p [n * 128 + f]; break;
      case 5: v = bt2p[n * 128 + f]; break;
      default: v = b3p[n * 64 + f]; break;   // i in 768..831
    }
    prm[i] = v;
  }

  // ---- x A-fragments: lane holds x[edge = e0+wrow+16rt+l15][d = 32s+8gq+j] ----
  bf16x8 ax[2][2];
#pragma unroll
  for (int rt = 0; rt < 2; ++rt) {
    int e = e0 + wrow + 16 * rt + l15;
    if (e >= E_TOT) e = E_TOT - 1;               // clamp; garbage never stored
    if (USEWS) {
#pragma unroll
      for (int s = 0; s < 2; ++s)
        ax[rt][s] = fragld(xb, e * 64 + s * 32 + 8 * gq);
    } else {
#pragma unroll
      for (int s = 0; s < 2; ++s)
        ax[rt][s] = frag_f32(xg + (size_t)e * 64 + s * 32 + 8 * gq);
    }
  }

  // weight fragment bases (fragment-contiguous bf16) or fp32 fallback
  const unsigned short* wf1 = wsW + (size_t)n * 32768;
  const unsigned short* wf2 = wf1 + 8192;
  const unsigned short* wf3 = wf1 + 24576;
  const float* W1n = W1c + (size_t)n * 8192;
  const float* W2n = W2p + (size_t)n * 16384;
  const float* W3n = W3p + (size_t)n * 8192;

  // B-fragment of W_l for frag (t,s): lane (l15,gq) elem j = W[16t+l15][32s+8gq+j]
  auto wfragA = [&](const unsigned short* wf, const float* Wn, int nfs, int t, int s, int K) {
    if (USEWS) return fragld(wf, ((t * nfs + s) << 9) + (lane << 3));
    return frag_f32(Wn + (16 * t + l15) * K + 32 * s + 8 * gq);
  };

  __syncthreads();   // prm ready (hs is per-wave, needs no barrier)

  f32x4 acc[2][8];

  // LN + SiLU + bf16 store of the wave's 32x128 slab into hs.
  // A already contains bias (folded into acc init).
  // D layout: col = feature 16ct+l15, row = edge 4gq+j (+16rt).
  auto ln_silu_store = [&](f32x4 (&A)[2][8], int pb) {
#pragma unroll
    for (int rt = 0; rt < 2; ++rt) {
      f32x4 sm4 = A[rt][0];
      f32x4 sq4 = A[rt][0] * A[rt][0];
#pragma unroll
      for (int ct = 1; ct < 8; ++ct) {
        f32x4 v = A[rt][ct];
        sm4 += v;
        sq4 += v * v;
      }
#pragma unroll
      for (int m = 1; m <= 8; m <<= 1) {
        f32x4 so, qo;
#pragma unroll
        for (int j = 0; j < 4; ++j) {
          so[j] = __shfl_xor(sm4[j], m);
          qo[j] = __shfl_xor(sq4[j], m);
        }
        sm4 += so;
        sq4 += qo;
      }
      f32x4 mu  = sm4 * (1.f / 128.f);
      f32x4 var = sq4 * (1.f / 128.f) - mu * mu;
      f32x4 rs;
#pragma unroll
      for (int j = 0; j < 4; ++j) rs[j] = __builtin_amdgcn_rsqf(var[j] + 1e-5f);
      int r0 = wrow + rt * 16 + 4 * gq;
#pragma unroll
      for (int ct = 0; ct < 8; ++ct) {
        float gv  = prm[pb + 128 + 16 * ct + l15];
        float btv = prm[pb + 256 + 16 * ct + l15];
        f32x4 t = (A[rt][ct] - mu) * rs;
#pragma unroll
        for (int j = 0; j < 4; ++j) {
          float v = t[j] * gv + btv;
          v = v * __builtin_amdgcn_rcpf(1.f + __expf(-v));   // silu
          BW bw; bw.h = (__bf16)v;
          hs[sidx(r0 + j, ct * 16 + l15, 128)] = bw.u;
        }
      }
    }
  };

  // ---- layer 1: [32 x 64] @ [64 x 128], C-in = b1 broadcast ----
#pragma unroll
  for (int ct = 0; ct < 8; ++ct) {
    float bv = prm[16 * ct + l15];
    f32x4 b4 = {bv, bv, bv, bv};
    acc[0][ct] = b4;
    acc[1][ct] = b4;
  }
#pragma unroll
  for (int s = 0; s < 2; ++s) {
#pragma unroll
    for (int ct = 0; ct < 8; ++ct) {
      bf16x8 b = wfragA(wf1, W1n, 2, ct, s, 64);
      acc[0][ct] = __builtin_amdgcn_mfma_f32_16x16x32_bf16(ax[0][s], b, acc[0][ct], 0, 0, 0);
      acc[1][ct] = __builtin_amdgcn_mfma_f32_16x16x32_bf16(ax[1][s], b, acc[1][ct], 0, 0, 0);
    }
  }
  ln_silu_store(acc, 0);

  // ---- layer 2: [32 x 128] @ [128 x 128], C-in = b2 broadcast ----
#pragma unroll
  for (int ct = 0; ct < 8; ++ct) {
    float bv = prm[384 + 16 * ct + l15];
    f32x4 b4 = {bv, bv, bv, bv};
    acc[0][ct] = b4;
    acc[1][ct] = b4;
  }
#pragma unroll
  for (int ks = 0; ks < 4; ++ks) {
    bf16x8 a0 = fragld(hs, sidx(wrow + l15,      ks * 32 + 8 * gq, 128));
    bf16x8 a1 = fragld(hs, sidx(wrow + 16 + l15, ks * 32 + 8 * gq, 128));
#pragma unroll
    for (int ct = 0; ct < 8; ++ct) {
      bf16x8 b = wfragA(wf2, W2n, 4, ct, ks, 128);
      acc[0][ct] = __builtin_amdgcn_mfma_f32_16x16x32_bf16(a0, b, acc[0][ct], 0, 0, 0);
      acc[1][ct] = __builtin_amdgcn_mfma_f32_16x16x32_bf16(a1, b, acc[1][ct], 0, 0, 0);
    }
  }
  ln_silu_store(acc, 384);

  // ---- layer 3: [32 x 128] @ [128 x 64], C-in = b3 broadcast, store ----
  f32x4 a3[2][4];
#pragma unroll
  for (int ct = 0; ct < 4; ++ct) {
    float bv = prm[768 + 16 * ct + l15];
    f32x4 b4 = {bv, bv, bv, bv};
    a3[0][ct] = b4;
    a3[1][ct] = b4;
  }
#pragma unroll
  for (int ks = 0; ks < 4; ++ks) {
    bf16x8 a0 = fragld(hs, sidx(wrow + l15,      ks * 32 + 8 * gq, 128));
    bf16x8 a1 = fragld(hs, sidx(wrow + 16 + l15, ks * 32 + 8 * gq, 128));
#pragma unroll
    for (int ct = 0; ct < 4; ++ct) {
      bf16x8 b = wfragA(wf3, W3n, 4, ct, ks, 128);
      a3[0][ct] = __builtin_amdgcn_mfma_f32_16x16x32_bf16(a0, b, a3[0][ct], 0, 0, 0);
      a3[1][ct] = __builtin_amdgcn_mfma_f32_16x16x32_bf16(a1, b, a3[1][ct], 0, 0, 0);
    }
  }

  // out[n][e][d], fp32. Lanes 0..15 cover 16 consecutive d -> 64B segments.
#pragma unroll
  for (int rt = 0; rt < 2; ++rt) {
#pragma unroll
    for (int j = 0; j < 4; ++j) {
      int e = e0 + wrow + rt * 16 + 4 * gq + j;
      if (e < E_TOT) {
        float* po = outp + ((size_t)n * E_TOT + e) * 64 + l15;
#pragma unroll
        for (int ct = 0; ct < 4; ++ct)
          po[ct * 16] = a3[rt][ct][j];
      }
    }
  }
}

extern "C" void kernel_launch(void* const* d_in, const int* in_sizes, int n_in,
                              void* d_out, int out_size, void* d_ws, size_t ws_size,
                              hipStream_t stream) {
  (void)in_sizes; (void)n_in; (void)out_size;
  const float* xg   = (const float*)d_in[0];
  const float* W1c  = (const float*)d_in[1];
  const float* b1c  = (const float*)d_in[2];
  const float* g1p  = (const float*)d_in[3];
  const float* bt1p = (const float*)d_in[4];
  const float* W2p  = (const float*)d_in[5];
  const float* b2p  = (const float*)d_in[6];
  const float* g2p  = (const float*)d_in[7];
  const float* bt2p = (const float*)d_in[8];
  const float* W3p  = (const float*)d_in[9];
  const float* b3p  = (const float*)d_in[10];
  float* outp = (float*)d_out;

  const size_t WS_W = (size_t)NEXP * 32768 * sizeof(unsigned short);  // 512 KB
  const size_t WS_X = (size_t)E_TOT * 64 * sizeof(unsigned short);    // 12.8 MB
  const bool usews = ws_size >= WS_W + WS_X;

  dim3 grid(NEXP * NTILE, 1, 1);
  dim3 block(256, 1, 1);

  if (usews) {
    unsigned short* wsW = (unsigned short*)d_ws;
    unsigned short* xb  = wsW + (size_t)NEXP * 32768;
    k_conv_w<<<1024, 256, 0, stream>>>(W1c, W2p, W3p, wsW);
    k_conv_x<<<3125, 256, 0, stream>>>(xg, xb);
    k_main<true><<<grid, block, 0, stream>>>(wsW, xb, xg, W1c, b1c, g1p, bt1p,
                                             W2p, b2p, g2p, bt2p, W3p, b3p, outp);
  } else {
    k_main<false><<<grid, block, 0, stream>>>(nullptr, nullptr, xg, W1c, b1c, g1p, bt1p,
                                              W2p, b2p, g2p, bt2p, W3p, b3p, outp);
  }
}

// Round 11
// 173.601 us; speedup vs baseline: 4.3976x; 1.0412x over previous
//
#include <hip/hip_runtime.h>

#define NEXP 8
#define E_TOT 100000
#define EPB 64                  // edges per block (4 waves x 16)
#define NTILE 1563              // ceil(E/EPB)

typedef __bf16 bf16x8 __attribute__((ext_vector_type(8)));
typedef float f32x4 __attribute__((ext_vector_type(4)));
typedef unsigned short u16x8 __attribute__((ext_vector_type(8)));

union BF8 { u16x8 u; bf16x8 b; };
union BW  { __bf16 h; unsigned short u; };

__device__ __forceinline__ unsigned short f2bf(float f) {
  unsigned int u = __float_as_uint(f);
  u += 0x7fffu + ((u >> 16) & 1u);           // RNE
  return (unsigned short)(u >> 16);
}

// XOR-swizzled element index: row r, col c, row stride (elems). (R1-validated)
__device__ __forceinline__ int sidx(int r, int c, int stride) {
  return r * stride + (c ^ ((r & 7) << 3));
}

__device__ __forceinline__ bf16x8 fragld(const unsigned short* a, int off) {
  BF8 t;
  t.u = *(const u16x8*)(a + off);
  return t.b;
}

__device__ __forceinline__ bf16x8 frag_f32(const float* s) {
  float4 u0 = *(const float4*)s;
  float4 u1 = *(const float4*)(s + 4);
  BF8 t;
  t.u[0]=f2bf(u0.x); t.u[1]=f2bf(u0.y); t.u[2]=f2bf(u0.z); t.u[3]=f2bf(u0.w);
  t.u[4]=f2bf(u1.x); t.u[5]=f2bf(u1.y); t.u[6]=f2bf(u1.z); t.u[7]=f2bf(u1.w);
  return t.b;
}

// ---- pre-kernel: weights fp32 -> bf16 in FRAGMENT-CONTIGUOUS layout ----
// Per expert n (32768 u16): L1 [0,8192) 16 frags, L2 [8192,24576) 32 frags,
// L3 [24576,32768) 16 frags. Each frag = 512 u16 = 64 lanes x 8 elems.
// Frag (t,s), lane (l15,gq), elem j holds W[16t+l15][32s+8gq+j]  (B-operand).
__global__ void k_conv_w(const float* __restrict__ W1c, const float* __restrict__ W2p,
                         const float* __restrict__ W3p, unsigned short* __restrict__ wsW) {
  int gid = blockIdx.x * 256 + threadIdx.x;     // [0, 262144)
  int n = gid >> 15, p = gid & 32767;
  int idx, frag, t, s;
  const float* base;
  int K;
  if (p < 8192)       { idx = p;         frag = idx >> 9; t = frag >> 1; s = frag & 1;
                        base = W1c + (size_t)n * 8192;  K = 64; }
  else if (p < 24576) { idx = p - 8192;  frag = idx >> 9; t = frag >> 2; s = frag & 3;
                        base = W2p + (size_t)n * 16384; K = 128; }
  else                { idx = p - 24576; frag = idx >> 9; t = frag >> 2; s = frag & 3;
                        base = W3p + (size_t)n * 8192;  K = 128; }
  int r = idx & 511, lane = r >> 3, j = r & 7;
  int l15 = lane & 15, gq = lane >> 4;
  wsW[gid] = f2bf(base[(16 * t + l15) * K + 32 * s + 8 * gq + j]);
}

// ---- pre-kernel: x fp32 -> bf16 ----
__global__ void k_conv_x(const float* __restrict__ xg, unsigned short* __restrict__ xb) {
  int gid = blockIdx.x * 256 + threadIdx.x;     // 800000 threads, 8 elems each
  const float* s = xg + (size_t)gid * 8;
  BF8 t;
  float4 a = *(const float4*)s, b = *(const float4*)(s + 4);
  t.u[0]=f2bf(a.x); t.u[1]=f2bf(a.y); t.u[2]=f2bf(a.z); t.u[3]=f2bf(a.w);
  t.u[4]=f2bf(b.x); t.u[5]=f2bf(b.y); t.u[6]=f2bf(b.z); t.u[7]=f2bf(b.w);
  *(u16x8*)(xb + (size_t)gid * 8) = t.u;
}

// ---- main kernel: R9/R10 structure, 16-edge waves for occupancy ----
// R11 rationale: R1/R9/R10 all pinned at ~21% occupancy / ~180-200us because
// acc[2][8] = 64 AGPRs + ~120 arch VGPRs = 184 total -> 2 waves/SIMD (unified
// register file; AGPRs invisible in rocprof VGPR_Count). Halving the wave tile
// (16 edges) halves the accumulator to 32 AGPRs -> ~150 total -> 3 waves/SIMD.
// launch_bounds(256,3) caps at 170 with ~20-reg margin (R7 lesson: only FAR
// over-cap causes scratch demotion).
template <bool USEWS>
__global__ __launch_bounds__(256, 3) void k_main(
    const unsigned short* __restrict__ wsW, const unsigned short* __restrict__ xb,
    const float* __restrict__ xg,
    const float* __restrict__ W1c, const float* __restrict__ b1c,
    const float* __restrict__ g1p, const float* __restrict__ bt1p,
    const float* __restrict__ W2p, const float* __restrict__ b2p,
    const float* __restrict__ g2p, const float* __restrict__ bt2p,
    const float* __restrict__ W3p, const float* __restrict__ b3p,
    float* __restrict__ outp)
{
  __shared__ __attribute__((aligned(16))) unsigned short hs[EPB * 128]; // 16 KB activations
  __shared__ __attribute__((aligned(16))) float prm[832];               // LN params + b3

  // bijective XCD remap (12504 = 8 * 1563 exact): each XCD owns a contiguous
  // tile range with all 8 experts -> x slab + weight set stay L2-hot.
  const int bid = blockIdx.x;
  const int g_  = (bid & 7) * NTILE + (bid >> 3);
  const int tile = g_ >> 3;
  const int n    = g_ & 7;
  const int e0   = tile * EPB;

  const int tid  = threadIdx.x;
  const int lane = tid & 63;
  const int wv   = tid >> 6;           // 0..3
  const int l15  = lane & 15;
  const int gq   = lane >> 4;          // 0..3
  const int wrow = wv * 16;            // wave's 16 edges within tile

  // ---- stage LN params (832 slots, 256 threads -> strided loop) ----
  for (int i = tid; i < 832; i += 256) {
    int grp = i >> 7, f = i & 127;
    float v;
    switch (grp) {
      case 0: v = b1c [n * 128 + f]; break;
      case 1: v = g1p [n * 128 + f]; break;
      case 2: v = bt1p[n * 128 + f]; break;
      case 3: v = b2p [n * 128 + f]; break;
      case 4: v = g2p [n * 128 + f]; break;
      case 5: v = bt2p[n * 128 + f]; break;
      default: v = b3p[n * 64 + f]; break;   // i in 768..831
    }
    prm[i] = v;
  }

  // ---- x A-fragment: lane holds x[edge = e0+wrow+l15][d = 32s+8gq+j] ----
  bf16x8 ax[2];
  {
    int e = e0 + wrow + l15;
    if (e >= E_TOT) e = E_TOT - 1;               // clamp; garbage never stored
    if (USEWS) {
#pragma unroll
      for (int s = 0; s < 2; ++s)
        ax[s] = fragld(xb, e * 64 + s * 32 + 8 * gq);
    } else {
#pragma unroll
      for (int s = 0; s < 2; ++s)
        ax[s] = frag_f32(xg + (size_t)e * 64 + s * 32 + 8 * gq);
    }
  }

  // weight fragment bases (fragment-contiguous bf16) or fp32 fallback
  const unsigned short* wf1 = wsW + (size_t)n * 32768;
  const unsigned short* wf2 = wf1 + 8192;
  const unsigned short* wf3 = wf1 + 24576;
  const float* W1n = W1c + (size_t)n * 8192;
  const float* W2n = W2p + (size_t)n * 16384;
  const float* W3n = W3p + (size_t)n * 8192;

  // B-fragment of W_l for frag (t,s): lane (l15,gq) elem j = W[16t+l15][32s+8gq+j]
  auto wfragA = [&](const unsigned short* wf, const float* Wn, int nfs, int t, int s, int K) {
    if (USEWS) return fragld(wf, ((t * nfs + s) << 9) + (lane << 3));
    return frag_f32(Wn + (16 * t + l15) * K + 32 * s + 8 * gq);
  };

  __syncthreads();   // prm ready (hs is per-wave, needs no barrier)

  f32x4 acc[8];

  // LN + SiLU + bf16 store of the wave's 16x128 slab into hs.
  // acc already contains bias (folded into init). D layout: col = 16ct+l15,
  // row = edge 4gq+j.
  auto ln_silu_store = [&](int pb) {
    f32x4 sm4 = acc[0];
    f32x4 sq4 = acc[0] * acc[0];
#pragma unroll
    for (int ct = 1; ct < 8; ++ct) {
      f32x4 v = acc[ct];
      sm4 += v;
      sq4 += v * v;
    }
#pragma unroll
    for (int m = 1; m <= 8; m <<= 1) {
      f32x4 so, qo;
#pragma unroll
      for (int j = 0; j < 4; ++j) {
        so[j] = __shfl_xor(sm4[j], m);
        qo[j] = __shfl_xor(sq4[j], m);
      }
      sm4 += so;
      sq4 += qo;
    }
    f32x4 mu  = sm4 * (1.f / 128.f);
    f32x4 var = sq4 * (1.f / 128.f) - mu * mu;
    f32x4 rs;
#pragma unroll
    for (int j = 0; j < 4; ++j) rs[j] = __builtin_amdgcn_rsqf(var[j] + 1e-5f);
    int r0 = wrow + 4 * gq;
#pragma unroll
    for (int ct = 0; ct < 8; ++ct) {
      float gv  = prm[pb + 128 + 16 * ct + l15];
      float btv = prm[pb + 256 + 16 * ct + l15];
      f32x4 t = (acc[ct] - mu) * rs;
#pragma unroll
      for (int j = 0; j < 4; ++j) {
        float v = t[j] * gv + btv;
        v = v * __builtin_amdgcn_rcpf(1.f + __expf(-v));   // silu
        BW bw; bw.h = (__bf16)v;
        hs[sidx(r0 + j, ct * 16 + l15, 128)] = bw.u;
      }
    }
  };

  // ---- layer 1: [16 x 64] @ [64 x 128], C-in = b1 broadcast ----
#pragma unroll
  for (int ct = 0; ct < 8; ++ct) {
    float bv = prm[16 * ct + l15];
    f32x4 b4 = {bv, bv, bv, bv};
    acc[ct] = b4;
  }
#pragma unroll
  for (int s = 0; s < 2; ++s) {
#pragma unroll
    for (int ct = 0; ct < 8; ++ct) {
      bf16x8 b = wfragA(wf1, W1n, 2, ct, s, 64);
      acc[ct] = __builtin_amdgcn_mfma_f32_16x16x32_bf16(ax[s], b, acc[ct], 0, 0, 0);
    }
  }
  ln_silu_store(0);

  // ---- layer 2: [16 x 128] @ [128 x 128], C-in = b2 broadcast ----
  f32x4 acc2[8];
#pragma unroll
  for (int ct = 0; ct < 8; ++ct) {
    float bv = prm[384 + 16 * ct + l15];
    f32x4 b4 = {bv, bv, bv, bv};
    acc2[ct] = b4;
  }
#pragma unroll
  for (int ks = 0; ks < 4; ++ks) {
    bf16x8 a0 = fragld(hs, sidx(wrow + l15, ks * 32 + 8 * gq, 128));
#pragma unroll
    for (int ct = 0; ct < 8; ++ct) {
      bf16x8 b = wfragA(wf2, W2n, 4, ct, ks, 128);
      acc2[ct] = __builtin_amdgcn_mfma_f32_16x16x32_bf16(a0, b, acc2[ct], 0, 0, 0);
    }
  }
#pragma unroll
  for (int ct = 0; ct < 8; ++ct) acc[ct] = acc2[ct];
  ln_silu_store(384);

  // ---- layer 3: [16 x 128] @ [128 x 64], C-in = b3 broadcast, store ----
  f32x4 a3[4];
#pragma unroll
  for (int ct = 0; ct < 4; ++ct) {
    float bv = prm[768 + 16 * ct + l15];
    f32x4 b4 = {bv, bv, bv, bv};
    a3[ct] = b4;
  }
#pragma unroll
  for (int ks = 0; ks < 4; ++ks) {
    bf16x8 a0 = fragld(hs, sidx(wrow + l15, ks * 32 + 8 * gq, 128));
#pragma unroll
    for (int ct = 0; ct < 4; ++ct) {
      bf16x8 b = wfragA(wf3, W3n, 4, ct, ks, 128);
      a3[ct] = __builtin_amdgcn_mfma_f32_16x16x32_bf16(a0, b, a3[ct], 0, 0, 0);
    }
  }

  // out[n][e][d], fp32. Lanes 0..15 cover 16 consecutive d -> 64B segments.
#pragma unroll
  for (int j = 0; j < 4; ++j) {
    int e = e0 + wrow + 4 * gq + j;
    if (e < E_TOT) {
      float* po = outp + ((size_t)n * E_TOT + e) * 64 + l15;
#pragma unroll
      for (int ct = 0; ct < 4; ++ct)
        po[ct * 16] = a3[ct][j];
    }
  }
}

extern "C" void kernel_launch(void* const* d_in, const int* in_sizes, int n_in,
                              void* d_out, int out_size, void* d_ws, size_t ws_size,
                              hipStream_t stream) {
  (void)in_sizes; (void)n_in; (void)out_size;
  const float* xg   = (const float*)d_in[0];
  const float* W1c  = (const float*)d_in[1];
  const float* b1c  = (const float*)d_in[2];
  const float* g1p  = (const float*)d_in[3];
  const float* bt1p = (const float*)d_in[4];
  const float* W2p  = (const float*)d_in[5];
  const float* b2p  = (const float*)d_in[6];
  const float* g2p  = (const float*)d_in[7];
  const float* bt2p = (const float*)d_in[8];
  const float* W3p  = (const float*)d_in[9];
  const float* b3p  = (const float*)d_in[10];
  float* outp = (float*)d_out;

  const size_t WS_W = (size_t)NEXP * 32768 * sizeof(unsigned short);  // 512 KB
  const size_t WS_X = (size_t)E_TOT * 64 * sizeof(unsigned short);    // 12.8 MB
  const bool usews = ws_size >= WS_W + WS_X;

  dim3 grid(NEXP * NTILE, 1, 1);
  dim3 block(256, 1, 1);

  if (usews) {
    unsigned short* wsW = (unsigned short*)d_ws;
    unsigned short* xb  = wsW + (size_t)NEXP * 32768;
    k_conv_w<<<1024, 256, 0, stream>>>(W1c, W2p, W3p, wsW);
    k_conv_x<<<3125, 256, 0, stream>>>(xg, xb);
    k_main<true><<<grid, block, 0, stream>>>(wsW, xb, xg, W1c, b1c, g1p, bt1p,
                                             W2p, b2p, g2p, bt2p, W3p, b3p, outp);
  } else {
    k_main<false><<<grid, block, 0, stream>>>(nullptr, nullptr, xg, W1c, b1c, g1p, bt1p,
                                              W2p, b2p, g2p, bt2p, W3p, b3p, outp);
  }
}

// Round 12
// 167.832 us; speedup vs baseline: 4.5487x; 1.0344x over previous
//
#include <hip/hip_runtime.h>

#define NEXP 8
#define E_TOT 100000
#define EPB 64                  // edges per block (4 waves x 16)
#define NTILE 1563              // ceil(E/EPB)

typedef __bf16 bf16x8 __attribute__((ext_vector_type(8)));
typedef float f32x4 __attribute__((ext_vector_type(4)));
typedef unsigned short u16x8 __attribute__((ext_vector_type(8)));

union BF8 { u16x8 u; bf16x8 b; };
union BW  { __bf16 h; unsigned short u; };

__device__ __forceinline__ unsigned short f2bf(float f) {
  unsigned int u = __float_as_uint(f);
  u += 0x7fffu + ((u >> 16) & 1u);           // RNE
  return (unsigned short)(u >> 16);
}

// XOR-swizzled element index: row r, col c, row stride (elems). (R1-validated)
__device__ __forceinline__ int sidx(int r, int c, int stride) {
  return r * stride + (c ^ ((r & 7) << 3));
}

__device__ __forceinline__ bf16x8 fragld(const unsigned short* a, int off) {
  BF8 t;
  t.u = *(const u16x8*)(a + off);
  return t.b;
}

__device__ __forceinline__ bf16x8 frag_f32(const float* s) {
  float4 u0 = *(const float4*)s;
  float4 u1 = *(const float4*)(s + 4);
  BF8 t;
  t.u[0]=f2bf(u0.x); t.u[1]=f2bf(u0.y); t.u[2]=f2bf(u0.z); t.u[3]=f2bf(u0.w);
  t.u[4]=f2bf(u1.x); t.u[5]=f2bf(u1.y); t.u[6]=f2bf(u1.z); t.u[7]=f2bf(u1.w);
  return t.b;
}

// ---- pre-kernel: weights fp32 -> bf16 in FRAGMENT-CONTIGUOUS layout ----
// Per expert n (32768 u16): L1 [0,8192) 16 frags, L2 [8192,24576) 32 frags,
// L3 [24576,32768) 16 frags. Each frag = 512 u16 = 64 lanes x 8 elems.
// L1/L2 frag (t,s), lane (l15,gq), elem j = W[16t+l15][32s+8gq+j] (B-operand).
// L3 is OUTPUT-ROW PERMUTED: frag (t,s) row slot l15 holds W3 row (4*l15 + t)
// so each lane owns 4 consecutive output features -> float4 out stores.
__global__ void k_conv_w(const float* __restrict__ W1c, const float* __restrict__ W2p,
                         const float* __restrict__ W3p, unsigned short* __restrict__ wsW) {
  int gid = blockIdx.x * 256 + threadIdx.x;     // [0, 262144)
  int n = gid >> 15, p = gid & 32767;
  int idx, frag, t, s, row;
  const float* base;
  int K;
  if (p < 8192)       { idx = p;         frag = idx >> 9; t = frag >> 1; s = frag & 1;
                        base = W1c + (size_t)n * 8192;  K = 64; }
  else if (p < 24576) { idx = p - 8192;  frag = idx >> 9; t = frag >> 2; s = frag & 3;
                        base = W2p + (size_t)n * 16384; K = 128; }
  else                { idx = p - 24576; frag = idx >> 9; t = frag >> 2; s = frag & 3;
                        base = W3p + (size_t)n * 8192;  K = 128; }
  int r = idx & 511, lane = r >> 3, j = r & 7;
  int l15 = lane & 15, gq = lane >> 4;
  row = (p < 24576) ? (16 * t + l15) : (4 * l15 + t);   // L3 permuted
  wsW[gid] = f2bf(base[row * K + 32 * s + 8 * gq + j]);
}

// ---- pre-kernel: x fp32 -> bf16 ----
__global__ void k_conv_x(const float* __restrict__ xg, unsigned short* __restrict__ xb) {
  int gid = blockIdx.x * 256 + threadIdx.x;     // 800000 threads, 8 elems each
  const float* s = xg + (size_t)gid * 8;
  BF8 t;
  float4 a = *(const float4*)s, b = *(const float4*)(s + 4);
  t.u[0]=f2bf(a.x); t.u[1]=f2bf(a.y); t.u[2]=f2bf(a.z); t.u[3]=f2bf(a.w);
  t.u[4]=f2bf(b.x); t.u[5]=f2bf(b.y); t.u[6]=f2bf(b.z); t.u[7]=f2bf(b.w);
  *(u16x8*)(xb + (size_t)gid * 8) = t.u;
}

// ---- main kernel: R11 structure + instruction/latency diet v2 ----
// R12 changes (value-neutral):
//  - LN params in 52 VGPRs (R1-validated); prm LDS + __syncthreads() deleted
//    (hs is per-wave-disjoint; waves fully independent)
//  - W3 row permutation -> out stores are 4x global_store_dwordx4
//  - b3 loaded as one float4
// Kept lessons: no wave_barrier/sched_barrier/mem-clobber asm; cap (256,3)=170
// leaves ~25-reg margin over the ~145 live set (R7: only far-over-cap spills).
template <bool USEWS>
__global__ __launch_bounds__(256, 3) void k_main(
    const unsigned short* __restrict__ wsW, const unsigned short* __restrict__ xb,
    const float* __restrict__ xg,
    const float* __restrict__ W1c, const float* __restrict__ b1c,
    const float* __restrict__ g1p, const float* __restrict__ bt1p,
    const float* __restrict__ W2p, const float* __restrict__ b2p,
    const float* __restrict__ g2p, const float* __restrict__ bt2p,
    const float* __restrict__ W3p, const float* __restrict__ b3p,
    float* __restrict__ outp)
{
  __shared__ __attribute__((aligned(16))) unsigned short hs[EPB * 128]; // 16 KB activations

  // bijective XCD remap (12504 = 8 * 1563 exact)
  const int bid = blockIdx.x;
  const int g_  = (bid & 7) * NTILE + (bid >> 3);
  const int tile = g_ >> 3;
  const int n    = g_ & 7;
  const int e0   = tile * EPB;

  const int tid  = threadIdx.x;
  const int lane = tid & 63;
  const int wv   = tid >> 6;           // 0..3
  const int l15  = lane & 15;
  const int gq   = lane >> 4;          // 0..3
  const int wrow = wv * 16;            // wave's 16 edges within tile

  // ---- LN params straight to registers (52 VGPR, L2-hot, coalesced 64B) ----
  float b1v[8], g1v[8], bt1v[8], b2v[8], g2v[8], bt2v[8];
#pragma unroll
  for (int ct = 0; ct < 8; ++ct) {
    int col = n * 128 + ct * 16 + l15;
    b1v[ct] = b1c[col];  g1v[ct] = g1p[col];  bt1v[ct] = bt1p[col];
    b2v[ct] = b2p[col];  g2v[ct] = g2p[col];  bt2v[ct] = bt2p[col];
  }
  float4 b34 = *(const float4*)(b3p + n * 64 + 4 * l15);  // permuted: o = 4*l15+t

  // ---- x A-fragment: lane holds x[edge = e0+wrow+l15][d = 32s+8gq+j] ----
  bf16x8 ax[2];
  {
    int e = e0 + wrow + l15;
    if (e >= E_TOT) e = E_TOT - 1;               // clamp; garbage never stored
    if (USEWS) {
#pragma unroll
      for (int s = 0; s < 2; ++s)
        ax[s] = fragld(xb, e * 64 + s * 32 + 8 * gq);
    } else {
#pragma unroll
      for (int s = 0; s < 2; ++s)
        ax[s] = frag_f32(xg + (size_t)e * 64 + s * 32 + 8 * gq);
    }
  }

  // weight fragment bases (fragment-contiguous bf16) or fp32 fallback
  const unsigned short* wf1 = wsW + (size_t)n * 32768;
  const unsigned short* wf2 = wf1 + 8192;
  const unsigned short* wf3 = wf1 + 24576;
  const float* W1n = W1c + (size_t)n * 8192;
  const float* W2n = W2p + (size_t)n * 16384;
  const float* W3n = W3p + (size_t)n * 8192;

  // fidx = linear fragment index in wsW layout; row = W row for fp32 fallback
  auto wfrag = [&](const unsigned short* wf, const float* Wn, int fidx, int row, int s, int K) {
    if (USEWS) return fragld(wf, (fidx << 9) + (lane << 3));
    return frag_f32(Wn + row * K + 32 * s + 8 * gq);
  };

  f32x4 acc[8];

  // LN + SiLU + bf16 store of the wave's 16x128 slab into hs.
  // acc already contains bias. D layout: col = 16ct+l15, row = edge 4gq+j.
  auto ln_silu_store = [&](const float (&gv)[8], const float (&btv)[8]) {
    f32x4 sm4 = acc[0];
    f32x4 sq4 = acc[0] * acc[0];
#pragma unroll
    for (int ct = 1; ct < 8; ++ct) {
      f32x4 v = acc[ct];
      sm4 += v;
      sq4 += v * v;
    }
#pragma unroll
    for (int m = 1; m <= 8; m <<= 1) {
      f32x4 so, qo;
#pragma unroll
      for (int j = 0; j < 4; ++j) {
        so[j] = __shfl_xor(sm4[j], m);
        qo[j] = __shfl_xor(sq4[j], m);
      }
      sm4 += so;
      sq4 += qo;
    }
    f32x4 mu  = sm4 * (1.f / 128.f);
    f32x4 var = sq4 * (1.f / 128.f) - mu * mu;
    f32x4 rs;
#pragma unroll
    for (int j = 0; j < 4; ++j) rs[j] = __builtin_amdgcn_rsqf(var[j] + 1e-5f);
    int r0 = wrow + 4 * gq;
#pragma unroll
    for (int ct = 0; ct < 8; ++ct) {
      f32x4 t = (acc[ct] - mu) * rs;
#pragma unroll
      for (int j = 0; j < 4; ++j) {
        float v = t[j] * gv[ct] + btv[ct];
        v = v * __builtin_amdgcn_rcpf(1.f + __expf(-v));   // silu
        BW bw; bw.h = (__bf16)v;
        hs[sidx(r0 + j, ct * 16 + l15, 128)] = bw.u;
      }
    }
  };

  // ---- layer 1: [16 x 64] @ [64 x 128], C-in = b1 broadcast ----
#pragma unroll
  for (int ct = 0; ct < 8; ++ct) {
    float bv = b1v[ct];
    f32x4 b4 = {bv, bv, bv, bv};
    acc[ct] = b4;
  }
#pragma unroll
  for (int s = 0; s < 2; ++s) {
#pragma unroll
    for (int ct = 0; ct < 8; ++ct) {
      bf16x8 b = wfrag(wf1, W1n, ct * 2 + s, 16 * ct + l15, s, 64);
      acc[ct] = __builtin_amdgcn_mfma_f32_16x16x32_bf16(ax[s], b, acc[ct], 0, 0, 0);
    }
  }
  ln_silu_store(g1v, bt1v);

  // ---- layer 2: [16 x 128] @ [128 x 128], C-in = b2 broadcast ----
  f32x4 acc2[8];
#pragma unroll
  for (int ct = 0; ct < 8; ++ct) {
    float bv = b2v[ct];
    f32x4 b4 = {bv, bv, bv, bv};
    acc2[ct] = b4;
  }
#pragma unroll
  for (int ks = 0; ks < 4; ++ks) {
    bf16x8 a0 = fragld(hs, sidx(wrow + l15, ks * 32 + 8 * gq, 128));
#pragma unroll
    for (int ct = 0; ct < 8; ++ct) {
      bf16x8 b = wfrag(wf2, W2n, ct * 4 + ks, 16 * ct + l15, ks, 128);
      acc2[ct] = __builtin_amdgcn_mfma_f32_16x16x32_bf16(a0, b, acc2[ct], 0, 0, 0);
    }
  }
#pragma unroll
  for (int ct = 0; ct < 8; ++ct) acc[ct] = acc2[ct];
  ln_silu_store(g2v, bt2v);

  // ---- layer 3: [16 x 128] @ [128 x 64] (row-permuted W3), store ----
  f32x4 a3[4];
#pragma unroll
  for (int t = 0; t < 4; ++t) {
    float bv = ((const float*)&b34)[t];
    f32x4 b4 = {bv, bv, bv, bv};
    a3[t] = b4;
  }
#pragma unroll
  for (int ks = 0; ks < 4; ++ks) {
    bf16x8 a0 = fragld(hs, sidx(wrow + l15, ks * 32 + 8 * gq, 128));
#pragma unroll
    for (int t = 0; t < 4; ++t) {
      bf16x8 b = wfrag(wf3, W3n, t * 4 + ks, 4 * l15 + t, ks, 128);
      a3[t] = __builtin_amdgcn_mfma_f32_16x16x32_bf16(a0, b, a3[t], 0, 0, 0);
    }
  }

  // out[n][e][d], fp32. Lane owns o = 4*l15..4*l15+3 (permuted W3) -> float4;
  // 16 lanes x 16B = 256B dense segments.
#pragma unroll
  for (int j = 0; j < 4; ++j) {
    int e = e0 + wrow + 4 * gq + j;
    if (e < E_TOT) {
      float4 o4;
      o4.x = a3[0][j]; o4.y = a3[1][j]; o4.z = a3[2][j]; o4.w = a3[3][j];
      *(float4*)(outp + ((size_t)n * E_TOT + e) * 64 + 4 * l15) = o4;
    }
  }
}

extern "C" void kernel_launch(void* const* d_in, const int* in_sizes, int n_in,
                              void* d_out, int out_size, void* d_ws, size_t ws_size,
                              hipStream_t stream) {
  (void)in_sizes; (void)n_in; (void)out_size;
  const float* xg   = (const float*)d_in[0];
  const float* W1c  = (const float*)d_in[1];
  const float* b1c  = (const float*)d_in[2];
  const float* g1p  = (const float*)d_in[3];
  const float* bt1p = (const float*)d_in[4];
  const float* W2p  = (const float*)d_in[5];
  const float* b2p  = (const float*)d_in[6];
  const float* g2p  = (const float*)d_in[7];
  const float* bt2p = (const float*)d_in[8];
  const float* W3p  = (const float*)d_in[9];
  const float* b3p  = (const float*)d_in[10];
  float* outp = (float*)d_out;

  const size_t WS_W = (size_t)NEXP * 32768 * sizeof(unsigned short);  // 512 KB
  const size_t WS_X = (size_t)E_TOT * 64 * sizeof(unsigned short);    // 12.8 MB
  const bool usews = ws_size >= WS_W + WS_X;

  dim3 grid(NEXP * NTILE, 1, 1);
  dim3 block(256, 1, 1);

  if (usews) {
    unsigned short* wsW = (unsigned short*)d_ws;
    unsigned short* xb  = wsW + (size_t)NEXP * 32768;
    k_conv_w<<<1024, 256, 0, stream>>>(W1c, W2p, W3p, wsW);
    k_conv_x<<<3125, 256, 0, stream>>>(xg, xb);
    k_main<true><<<grid, block, 0, stream>>>(wsW, xb, xg, W1c, b1c, g1p, bt1p,
                                             W2p, b2p, g2p, bt2p, W3p, b3p, outp);
  } else {
    k_main<false><<<grid, block, 0, stream>>>(nullptr, nullptr, xg, W1c, b1c, g1p, bt1p,
                                              W2p, b2p, g2p, bt2p, W3p, b3p, outp);
  }
}